// Round 8
// baseline (132.173 us; speedup 1.0000x reference)
//
#include <hip/hip_runtime.h>

#define BLOCK 512
typedef float v2f __attribute__((ext_vector_type(2)));

// ---------- packed fp32 (VOP3P) ----------
__device__ __forceinline__ v2f pk_fma(v2f a, v2f b, v2f c) {
  v2f d;
  asm("v_pk_fma_f32 %0, %1, %2, %3" : "=v"(d) : "v"(a), "v"(b), "v"(c));
  return d;
}
__device__ __forceinline__ v2f pk_mul(v2f a, v2f b) {
  v2f d;
  asm("v_pk_mul_f32 %0, %1, %2" : "=v"(d) : "v"(a), "v"(b));
  return d;
}
// d = (s.lo * p.hi, s.hi * p.lo)  -- component-swapped src1 via op_sel
__device__ __forceinline__ v2f pk_mul_swap(v2f s, v2f p) {
  v2f d;
  asm("v_pk_mul_f32 %0, %1, %2 op_sel:[0,1] op_sel_hi:[1,0]" : "=v"(d) : "v"(s), "v"(p));
  return d;
}

// ---------- cross-lane xor within 16-lane rows (butterfly reduces) ----------
template<int CTRL>
__device__ __forceinline__ float dpp_f(float v) {
  return __int_as_float(__builtin_amdgcn_mov_dpp(__float_as_int(v), CTRL, 0xF, 0xF, true));
}
template<int MASK>
__device__ __forceinline__ float shx(float v) {
  if constexpr (MASK == 1)      return dpp_f<0xB1>(v);   // quad_perm xor1
  else if constexpr (MASK == 2) return dpp_f<0x4E>(v);   // quad_perm xor2
  else if constexpr (MASK == 8) return dpp_f<0x128>(v);  // row_ror:8 == xor8 in row16
  else  // MASK == 4: ds_swizzle BitMode xor=4
    return __int_as_float(__builtin_amdgcn_ds_swizzle(__float_as_int(v), 0x101F));
}

// forward one-layer index map in X basis
__device__ __forceinline__ int gmap(int b) {
#pragma unroll
  for (int j = 0; j < 7; ++j) b ^= ((b >> (j + 1)) & 1) << j;
  b ^= (b & 1) << 7;
  return b;
}

// masks m_q = p^3(e_q): q0..q7 -> 0x32,0x56,0xAC,0x59,0xB3,0x66,0xCC,0x99
#define MQ_PACKED 0x99CC66B359AC5632ULL

// build X-basis product-state pieces for one sample row
__device__ __forceinline__ void build_w(const float* th, int u, v2f* wr2, float* wup) {
  float uf[8], vf[8];
#pragma unroll
  for (int q = 0; q < 8; ++q) {
    const float h = 0.5f * th[q];
    const float c_ = __cosf(h), s_ = __sinf(h);
    uf[q] = c_ + s_; vf[q] = c_ - s_;
  }
  v2f P01; P01.x = uf[0]; P01.y = vf[0];
  const float r12[4] = {uf[1] * uf[2], vf[1] * uf[2], uf[1] * vf[2], vf[1] * vf[2]};
#pragma unroll
  for (int k = 0; k < 8; ++k) {
    const float rest = r12[k & 3] * ((k & 4) ? vf[3] : uf[3]);
    v2f rr; rr.x = rest; rr.y = rest;
    wr2[k] = pk_mul(P01, rr);
  }
  const bool b4 = (u & 1), b5 = (u & 2), b6 = (u & 4), b7 = (u & 8);
  const float f4 = b4 ? vf[4] : uf[4], g4 = b4 ? uf[4] : vf[4];
  const float f5 = b5 ? vf[5] : uf[5], g5 = b5 ? uf[5] : vf[5];
  const float f6 = b6 ? vf[6] : uf[6], g6 = b6 ? uf[6] : vf[6];
  const float f7 = b7 ? vf[7] : uf[7], g7 = b7 ? uf[7] : vf[7];
  const float A0 = f4 * f5, A1 = g4 * f5, A2 = f4 * g5, A3 = g4 * g5;
  const float B0 = f6 * f7, B1 = g6 * f7, B2 = f6 * g7, B3 = g6 * g7;
  const float wu = A0 * B0;
  wup[0] = wu * (A3 * B0);   // mL=3
  wup[1] = wu * (A1 * B1);   // mL=5
  wup[2] = wu * (A2 * B2);   // mL=A
  wup[3] = wup[1];           // mL=5
  wup[4] = wu * (A3 * B2);   // mL=B
  wup[5] = wu * (A2 * B1);   // mL=6
  wup[6] = wu * (A0 * B3);   // mL=C
  wup[7] = wu * (A1 * B2);   // mL=9
}

// ---- Phase C helpers: K table read as float4 (4 r-values per lane) ----
template<int Q, int XOR, bool SWAP>
__device__ __forceinline__ void dot1(const float4* kb4, const v2f* wA, const v2f* wB,
                                     float wupA, float wupB, float& zA, float& zB) {
  v2f aA, aB; aA.x = aA.y = 0.f; aB.x = aB.y = 0.f;
#pragma unroll
  for (int k2 = 0; k2 < 4; ++k2) {
    const float4 kv = kb4[(Q * 4 + k2) * 16];
    v2f klo; klo.x = kv.x; klo.y = kv.y;
    v2f khi; khi.x = kv.z; khi.y = kv.w;
    const int k0 = 2 * k2, k1 = 2 * k2 + 1;
    v2f pA0 = SWAP ? pk_mul_swap(wA[k0], wA[k0 ^ XOR]) : pk_mul(wA[k0], wA[k0 ^ XOR]);
    v2f pA1 = SWAP ? pk_mul_swap(wA[k1], wA[k1 ^ XOR]) : pk_mul(wA[k1], wA[k1 ^ XOR]);
    v2f pB0 = SWAP ? pk_mul_swap(wB[k0], wB[k0 ^ XOR]) : pk_mul(wB[k0], wB[k0 ^ XOR]);
    v2f pB1 = SWAP ? pk_mul_swap(wB[k1], wB[k1 ^ XOR]) : pk_mul(wB[k1], wB[k1 ^ XOR]);
    aA = pk_fma(pA0, klo, aA);
    aA = pk_fma(pA1, khi, aA);
    aB = pk_fma(pB0, klo, aB);
    aB = pk_fma(pB1, khi, aB);
  }
  zA = (aA.x + aA.y) * wupA;
  zB = (aB.x + aB.y) * wupB;
}
template<int Q1, int Q2, int XOR, bool SWAP>
__device__ __forceinline__ void dot2(const float4* kb4, const v2f* wA, const v2f* wB,
                                     float wupA1, float wupA2, float wupB1, float wupB2,
                                     float& zA1, float& zA2, float& zB1, float& zB2) {
  v2f a1A, a2A, a1B, a2B;
  a1A.x = a1A.y = a2A.x = a2A.y = 0.f;
  a1B.x = a1B.y = a2B.x = a2B.y = 0.f;
#pragma unroll
  for (int k2 = 0; k2 < 4; ++k2) {
    const float4 kv1 = kb4[(Q1 * 4 + k2) * 16];
    const float4 kv2 = kb4[(Q2 * 4 + k2) * 16];
    v2f k1lo; k1lo.x = kv1.x; k1lo.y = kv1.y;
    v2f k1hi; k1hi.x = kv1.z; k1hi.y = kv1.w;
    v2f k2lo; k2lo.x = kv2.x; k2lo.y = kv2.y;
    v2f k2hi; k2hi.x = kv2.z; k2hi.y = kv2.w;
    const int k0 = 2 * k2, k1 = 2 * k2 + 1;
    v2f pA0 = SWAP ? pk_mul_swap(wA[k0], wA[k0 ^ XOR]) : pk_mul(wA[k0], wA[k0 ^ XOR]);
    v2f pA1 = SWAP ? pk_mul_swap(wA[k1], wA[k1 ^ XOR]) : pk_mul(wA[k1], wA[k1 ^ XOR]);
    v2f pB0 = SWAP ? pk_mul_swap(wB[k0], wB[k0 ^ XOR]) : pk_mul(wB[k0], wB[k0 ^ XOR]);
    v2f pB1 = SWAP ? pk_mul_swap(wB[k1], wB[k1 ^ XOR]) : pk_mul(wB[k1], wB[k1 ^ XOR]);
    a1A = pk_fma(pA0, k1lo, a1A); a1A = pk_fma(pA1, k1hi, a1A);
    a2A = pk_fma(pA0, k2lo, a2A); a2A = pk_fma(pA1, k2hi, a2A);
    a1B = pk_fma(pB0, k1lo, a1B); a1B = pk_fma(pB1, k1hi, a1B);
    a2B = pk_fma(pB0, k2lo, a2B); a2B = pk_fma(pB1, k2hi, a2B);
  }
  zA1 = (a1A.x + a1A.y) * wupA1;
  zA2 = (a2A.x + a2A.y) * wupA2;
  zB1 = (a1B.x + a1B.y) * wupB1;
  zB2 = (a2B.x + a2B.y) * wupB2;
}

// ================= Kernel 1: x -> z (stored in first 8 floats of each out row) =================
__global__ __launch_bounds__(BLOCK, 4) void qcnn_z(
    const float* __restrict__ x,   const float* __restrict__ fcw,
    const float* __restrict__ fcb, const float* __restrict__ qp,
    float* __restrict__ out)
{
  __shared__ float s_fcw[8 * 512];        // 16 KB
  __shared__ float s_beta[256];           //  1 KB
  __shared__ float s_K3[8][4][16][4];     //  8 KB

  const int tid = threadIdx.x;
  const int wave = tid >> 6;
  const int lane = tid & 63;
  const int u = lane & 15;
  const int g = lane >> 4;

  const int base = blockIdx.x * 64 + wave * 8;
  const int sA = base + g;
  const int sB = base + 4 + g;

  // x prefetch first: HBM latency overlaps the whole prologue
  const float* xrA = x + (size_t)sA * 512 + u * 4;
  const float* xrB = x + (size_t)sB * 512 + u * 4;
  float4 xpa[8], xpb[8];
#pragma unroll
  for (int t = 0; t < 8; ++t) xpa[t] = *(const float4*)(xrA + t * 64);
#pragma unroll
  for (int t = 0; t < 8; ++t) xpb[t] = *(const float4*)(xrB + t * 64);

  for (int i = tid; i < 1024; i += BLOCK)
    ((float4*)s_fcw)[i] = ((const float4*)fcw)[i];
  if (tid < 256) {
    const int c = tid;
    const int i1 = gmap(c);
    const int i2 = gmap(i1);
    float ang = 0.f;
#pragma unroll
    for (int q = 0; q < 8; ++q) {
      ang += (((c  >> q) & 1) ? 0.5f : -0.5f) * qp[q];
      ang += (((i1 >> q) & 1) ? 0.5f : -0.5f) * qp[8 + q];
      ang += (((i2 >> q) & 1) ? 0.5f : -0.5f) * qp[16 + q];
    }
    s_beta[c] = ang;
  }
  __syncthreads();

  for (int i = tid; i < 2048; i += BLOCK) {
    const int q = i >> 8, c = i & 255;
    const int m = (int)((MQ_PACKED >> (8 * q)) & 0xFF);
    const float kv = __cosf(s_beta[c ^ m] - s_beta[c]) * (1.0f / 256.0f);
    s_K3[q][(c & 15) >> 2][c >> 4][c & 3] = kv;
  }
  __syncthreads();

  // Phase A
  v2f accA[8], accB[8];
#pragma unroll
  for (int q = 0; q < 8; ++q) {
    accA[q].x = 0.f; accA[q].y = 0.f;
    accB[q].x = 0.f; accB[q].y = 0.f;
  }
#pragma unroll
  for (int t = 0; t < 8; ++t) {
    const float4 xa = xpa[t];
    const float4 xb = xpb[t];
    v2f xa01; xa01.x = xa.x; xa01.y = xa.y;
    v2f xa23; xa23.x = xa.z; xa23.y = xa.w;
    v2f xb01; xb01.x = xb.x; xb01.y = xb.y;
    v2f xb23; xb23.x = xb.z; xb23.y = xb.w;
#pragma unroll
    for (int q = 0; q < 8; ++q) {
      const float4 wv = *(const float4*)(s_fcw + q * 512 + u * 4 + t * 64);
      v2f w01; w01.x = wv.x; w01.y = wv.y;
      v2f w23; w23.x = wv.z; w23.y = wv.w;
      accA[q] = pk_fma(xa01, w01, accA[q]);
      accA[q] = pk_fma(xa23, w23, accA[q]);
      accB[q] = pk_fma(xb01, w01, accB[q]);
      accB[q] = pk_fma(xb23, w23, accB[q]);
    }
  }
  float thA[8], thB[8];
#pragma unroll
  for (int q = 0; q < 8; ++q) {
    float aA = accA[q].x + accA[q].y;
    float aB = accB[q].x + accB[q].y;
    aA += shx<1>(aA); aB += shx<1>(aB);
    aA += shx<2>(aA); aB += shx<2>(aB);
    aA += shx<4>(aA); aB += shx<4>(aB);
    aA += shx<8>(aA); aB += shx<8>(aB);
    const float fb = fcb[q];
    thA[q] = aA + fb; thB[q] = aB + fb;
  }

  // Phase B
  v2f wA[8], wB[8];
  float wupA[8], wupB[8];
  build_w(thA, u, wA, wupA);
  build_w(thB, u, wB, wupB);

  // Phase C
  float zpA[8], zpB[8];
  {
    const float4* kb4 = ((const float4*)s_K3) + u;
    dot1<0, 1, false>(kb4, wA, wB, wupA[0], wupB[0], zpA[0], zpB[0]);
    dot1<4, 1, true >(kb4, wA, wB, wupA[4], wupB[4], zpA[4], zpB[4]);
    dot2<1, 5, 3, false>(kb4, wA, wB, wupA[1], wupA[5], wupB[1], wupB[5],
                         zpA[1], zpA[5], zpB[1], zpB[5]);
    dot2<2, 6, 6, false>(kb4, wA, wB, wupA[2], wupA[6], wupB[2], wupB[6],
                         zpA[2], zpA[6], zpB[2], zpB[6]);
    dot2<3, 7, 4, true >(kb4, wA, wB, wupA[3], wupA[7], wupB[3], wupB[7],
                         zpA[3], zpA[7], zpB[3], zpB[7]);
  }
  // lane reduce (broadcast)
#pragma unroll
  for (int q = 0; q < 8; ++q) { zpA[q] += shx<1>(zpA[q]); zpB[q] += shx<1>(zpB[q]); }
#pragma unroll
  for (int q = 0; q < 8; ++q) { zpA[q] += shx<2>(zpA[q]); zpB[q] += shx<2>(zpB[q]); }
#pragma unroll
  for (int q = 0; q < 8; ++q) { zpA[q] += shx<4>(zpA[q]); zpB[q] += shx<4>(zpB[q]); }
#pragma unroll
  for (int q = 0; q < 8; ++q) { zpA[q] += shx<8>(zpA[q]); zpB[q] += shx<8>(zpB[q]); }

  // store z into the first 8 floats of each sample's out row
  if (u == 0) {
    float4 z0, z1;
    z0.x = zpA[0]; z0.y = zpA[1]; z0.z = zpA[2]; z0.w = zpA[3];
    z1.x = zpA[4]; z1.y = zpA[5]; z1.z = zpA[6]; z1.w = zpA[7];
    *(float4*)(out + (size_t)sA * 512)     = z0;
    *(float4*)(out + (size_t)sA * 512 + 4) = z1;
    z0.x = zpB[0]; z0.y = zpB[1]; z0.z = zpB[2]; z0.w = zpB[3];
    z1.x = zpB[4]; z1.y = zpB[5]; z1.z = zpB[6]; z1.w = zpB[7];
    *(float4*)(out + (size_t)sB * 512)     = z0;
    *(float4*)(out + (size_t)sB * 512 + 4) = z1;
  }
}

// ================= Kernel 2: z -> out (pure streaming GEMM 8 -> 512) =================
__global__ __launch_bounds__(BLOCK, 4) void qcnn_out(
    const float* __restrict__ pw, const float* __restrict__ pb,
    float* out)
{
  __shared__ float s_pwt[8 * 512];   // [q][o] transposed, 16 KB
  __shared__ float s_pb[512];        // 2 KB

  const int tid = threadIdx.x;
  // pw natural [512][8] -> transposed s_pwt[q][o]; coalesced float4 read,
  // scalar ds_writes land 2-way per bank (free).
  for (int i = tid; i < 1024; i += BLOCK) {
    const float4 v = ((const float4*)pw)[i];
    const int row = i >> 1, c0 = 4 * (i & 1);
    s_pwt[(c0 + 0) * 512 + row] = v.x;
    s_pwt[(c0 + 1) * 512 + row] = v.y;
    s_pwt[(c0 + 2) * 512 + row] = v.z;
    s_pwt[(c0 + 3) * 512 + row] = v.w;
  }
  if (tid < 128) ((float4*)s_pb)[tid] = ((const float4*)pb)[tid];
  __syncthreads();

  const int wave = tid >> 6;
  const int lane = tid & 63;
  const int u = lane & 15;
  const int g = lane >> 4;

  const int base = blockIdx.x * 64 + wave * 8;
  const int sA = base + g;
  const int sB = base + 4 + g;

  float* orA = out + (size_t)sA * 512;
  float* orB = out + (size_t)sB * 512;

  // read z (written by qcnn_z into the row head); loads precede all stores
  // of this wave in program order, so the overwrite below is safe.
  const float4 zA0 = *(const float4*)(orA);
  const float4 zA1 = *(const float4*)(orA + 4);
  const float4 zB0 = *(const float4*)(orB);
  const float4 zB1 = *(const float4*)(orB + 4);

  v2f zzA[8], zzB[8];
  const float zAv[8] = {zA0.x, zA0.y, zA0.z, zA0.w, zA1.x, zA1.y, zA1.z, zA1.w};
  const float zBv[8] = {zB0.x, zB0.y, zB0.z, zB0.w, zB1.x, zB1.y, zB1.z, zB1.w};
#pragma unroll
  for (int q = 0; q < 8; ++q) {
    zzA[q].x = zAv[q]; zzA[q].y = zAv[q];
    zzB[q].x = zBv[q]; zzB[q].y = zBv[q];
  }

#pragma unroll
  for (int tt = 0; tt < 8; ++tt) {
    const int o = u * 4 + tt * 64;
    const float4 pbv = *(const float4*)(s_pb + o);
    v2f rA0; rA0.x = pbv.x; rA0.y = pbv.y;
    v2f rA1; rA1.x = pbv.z; rA1.y = pbv.w;
    v2f rB0 = rA0, rB1 = rA1;
#pragma unroll
    for (int q = 0; q < 8; ++q) {
      const float4 wv = *(const float4*)(s_pwt + q * 512 + o);
      v2f w01; w01.x = wv.x; w01.y = wv.y;
      v2f w23; w23.x = wv.z; w23.y = wv.w;
      rA0 = pk_fma(zzA[q], w01, rA0);
      rA1 = pk_fma(zzA[q], w23, rA1);
      rB0 = pk_fma(zzB[q], w01, rB0);
      rB1 = pk_fma(zzB[q], w23, rB1);
    }
    float4 ovA; ovA.x = rA0.x; ovA.y = rA0.y; ovA.z = rA1.x; ovA.w = rA1.y;
    float4 ovB; ovB.x = rB0.x; ovB.y = rB0.y; ovB.z = rB1.x; ovB.w = rB1.y;
    *(float4*)(orA + o) = ovA;
    *(float4*)(orB + o) = ovB;
  }
}

extern "C" void kernel_launch(void* const* d_in, const int* in_sizes, int n_in,
                              void* d_out, int out_size, void* d_ws, size_t ws_size,
                              hipStream_t stream) {
  const float* x   = (const float*)d_in[0];
  const float* fcw = (const float*)d_in[1];
  const float* fcb = (const float*)d_in[2];
  const float* qp  = (const float*)d_in[3];
  const float* pw  = (const float*)d_in[4];
  const float* pb  = (const float*)d_in[5];
  float* out = (float*)d_out;

  dim3 grid(512), block(BLOCK);
  hipLaunchKernelGGL(qcnn_z,   grid, block, 0, stream, x, fcw, fcb, qp, out);
  hipLaunchKernelGGL(qcnn_out, grid, block, 0, stream, pw, pb, out);
}

// Round 10
// 121.974 us; speedup vs baseline: 1.0836x; 1.0836x over previous
//
#include <hip/hip_runtime.h>

#define BLOCK 512
typedef float v2f __attribute__((ext_vector_type(2)));
typedef float v4f __attribute__((ext_vector_type(4)));   // clang-native for nontemporal builtin

// ---------- packed fp32 (VOP3P) ----------
__device__ __forceinline__ v2f pk_fma(v2f a, v2f b, v2f c) {
  v2f d;
  asm("v_pk_fma_f32 %0, %1, %2, %3" : "=v"(d) : "v"(a), "v"(b), "v"(c));
  return d;
}
__device__ __forceinline__ v2f pk_mul(v2f a, v2f b) {
  v2f d;
  asm("v_pk_mul_f32 %0, %1, %2" : "=v"(d) : "v"(a), "v"(b));
  return d;
}
// d = (s.lo * p.hi, s.hi * p.lo)  -- component-swapped src1 via op_sel
__device__ __forceinline__ v2f pk_mul_swap(v2f s, v2f p) {
  v2f d;
  asm("v_pk_mul_f32 %0, %1, %2 op_sel:[0,1] op_sel_hi:[1,0]" : "=v"(d) : "v"(s), "v"(p));
  return d;
}

// ---------- cross-lane xor within 16-lane rows (butterfly reduces) ----------
template<int CTRL>
__device__ __forceinline__ float dpp_f(float v) {
  return __int_as_float(__builtin_amdgcn_mov_dpp(__float_as_int(v), CTRL, 0xF, 0xF, true));
}
template<int MASK>
__device__ __forceinline__ float shx(float v) {
  if constexpr (MASK == 1)      return dpp_f<0xB1>(v);   // quad_perm xor1
  else if constexpr (MASK == 2) return dpp_f<0x4E>(v);   // quad_perm xor2
  else if constexpr (MASK == 8) return dpp_f<0x128>(v);  // row_ror:8 == xor8 in row16
  else  // MASK == 4: ds_swizzle BitMode xor=4
    return __int_as_float(__builtin_amdgcn_ds_swizzle(__float_as_int(v), 0x101F));
}

// forward one-layer index map in X basis
__device__ __forceinline__ int gmap(int b) {
#pragma unroll
  for (int j = 0; j < 7; ++j) b ^= ((b >> (j + 1)) & 1) << j;
  b ^= (b & 1) << 7;
  return b;
}

// masks m_q = p^3(e_q): q0..q7 -> 0x32,0x56,0xAC,0x59,0xB3,0x66,0xCC,0x99
#define MQ_PACKED 0x99CC66B359AC5632ULL

// build X-basis product-state pieces for one sample row
__device__ __forceinline__ void build_w(const float* th, int u, v2f* wr2, float* wup) {
  float uf[8], vf[8];
#pragma unroll
  for (int q = 0; q < 8; ++q) {
    const float h = 0.5f * th[q];
    const float c_ = __cosf(h), s_ = __sinf(h);
    uf[q] = c_ + s_; vf[q] = c_ - s_;
  }
  v2f P01; P01.x = uf[0]; P01.y = vf[0];
  const float r12[4] = {uf[1] * uf[2], vf[1] * uf[2], uf[1] * vf[2], vf[1] * vf[2]};
#pragma unroll
  for (int k = 0; k < 8; ++k) {
    const float rest = r12[k & 3] * ((k & 4) ? vf[3] : uf[3]);
    v2f rr; rr.x = rest; rr.y = rest;
    wr2[k] = pk_mul(P01, rr);
  }
  const bool b4 = (u & 1), b5 = (u & 2), b6 = (u & 4), b7 = (u & 8);
  const float f4 = b4 ? vf[4] : uf[4], g4 = b4 ? uf[4] : vf[4];
  const float f5 = b5 ? vf[5] : uf[5], g5 = b5 ? uf[5] : vf[5];
  const float f6 = b6 ? vf[6] : uf[6], g6 = b6 ? uf[6] : vf[6];
  const float f7 = b7 ? vf[7] : uf[7], g7 = b7 ? uf[7] : vf[7];
  const float A0 = f4 * f5, A1 = g4 * f5, A2 = f4 * g5, A3 = g4 * g5;
  const float B0 = f6 * f7, B1 = g6 * f7, B2 = f6 * g7, B3 = g6 * g7;
  const float wu = A0 * B0;
  wup[0] = wu * (A3 * B0);   // mL=3
  wup[1] = wu * (A1 * B1);   // mL=5
  wup[2] = wu * (A2 * B2);   // mL=A
  wup[3] = wup[1];           // mL=5
  wup[4] = wu * (A3 * B2);   // mL=B
  wup[5] = wu * (A2 * B1);   // mL=6
  wup[6] = wu * (A0 * B3);   // mL=C
  wup[7] = wu * (A1 * B2);   // mL=9
}

// ---- Phase C helpers: K table read as float4 (4 r-values per lane) ----
template<int Q, int XOR, bool SWAP>
__device__ __forceinline__ void dot1(const float4* kb4, const v2f* wA, const v2f* wB,
                                     float wupA, float wupB, float& zA, float& zB) {
  v2f aA, aB; aA.x = aA.y = 0.f; aB.x = aB.y = 0.f;
#pragma unroll
  for (int k2 = 0; k2 < 4; ++k2) {
    const float4 kv = kb4[(Q * 4 + k2) * 16];
    v2f klo; klo.x = kv.x; klo.y = kv.y;
    v2f khi; khi.x = kv.z; khi.y = kv.w;
    const int k0 = 2 * k2, k1 = 2 * k2 + 1;
    v2f pA0 = SWAP ? pk_mul_swap(wA[k0], wA[k0 ^ XOR]) : pk_mul(wA[k0], wA[k0 ^ XOR]);
    v2f pA1 = SWAP ? pk_mul_swap(wA[k1], wA[k1 ^ XOR]) : pk_mul(wA[k1], wA[k1 ^ XOR]);
    v2f pB0 = SWAP ? pk_mul_swap(wB[k0], wB[k0 ^ XOR]) : pk_mul(wB[k0], wB[k0 ^ XOR]);
    v2f pB1 = SWAP ? pk_mul_swap(wB[k1], wB[k1 ^ XOR]) : pk_mul(wB[k1], wB[k1 ^ XOR]);
    aA = pk_fma(pA0, klo, aA);
    aA = pk_fma(pA1, khi, aA);
    aB = pk_fma(pB0, klo, aB);
    aB = pk_fma(pB1, khi, aB);
  }
  zA = (aA.x + aA.y) * wupA;
  zB = (aB.x + aB.y) * wupB;
}
template<int Q1, int Q2, int XOR, bool SWAP>
__device__ __forceinline__ void dot2(const float4* kb4, const v2f* wA, const v2f* wB,
                                     float wupA1, float wupA2, float wupB1, float wupB2,
                                     float& zA1, float& zA2, float& zB1, float& zB2) {
  v2f a1A, a2A, a1B, a2B;
  a1A.x = a1A.y = a2A.x = a2A.y = 0.f;
  a1B.x = a1B.y = a2B.x = a2B.y = 0.f;
#pragma unroll
  for (int k2 = 0; k2 < 4; ++k2) {
    const float4 kv1 = kb4[(Q1 * 4 + k2) * 16];
    const float4 kv2 = kb4[(Q2 * 4 + k2) * 16];
    v2f k1lo; k1lo.x = kv1.x; k1lo.y = kv1.y;
    v2f k1hi; k1hi.x = kv1.z; k1hi.y = kv1.w;
    v2f k2lo; k2lo.x = kv2.x; k2lo.y = kv2.y;
    v2f k2hi; k2hi.x = kv2.z; k2hi.y = kv2.w;
    const int k0 = 2 * k2, k1 = 2 * k2 + 1;
    v2f pA0 = SWAP ? pk_mul_swap(wA[k0], wA[k0 ^ XOR]) : pk_mul(wA[k0], wA[k0 ^ XOR]);
    v2f pA1 = SWAP ? pk_mul_swap(wA[k1], wA[k1 ^ XOR]) : pk_mul(wA[k1], wA[k1 ^ XOR]);
    v2f pB0 = SWAP ? pk_mul_swap(wB[k0], wB[k0 ^ XOR]) : pk_mul(wB[k0], wB[k0 ^ XOR]);
    v2f pB1 = SWAP ? pk_mul_swap(wB[k1], wB[k1 ^ XOR]) : pk_mul(wB[k1], wB[k1 ^ XOR]);
    a1A = pk_fma(pA0, k1lo, a1A); a1A = pk_fma(pA1, k1hi, a1A);
    a2A = pk_fma(pA0, k2lo, a2A); a2A = pk_fma(pA1, k2hi, a2A);
    a1B = pk_fma(pB0, k1lo, a1B); a1B = pk_fma(pB1, k1hi, a1B);
    a2B = pk_fma(pB0, k2lo, a2B); a2B = pk_fma(pB1, k2hi, a2B);
  }
  zA1 = (a1A.x + a1A.y) * wupA1;
  zA2 = (a2A.x + a2A.y) * wupA2;
  zB1 = (a1B.x + a1B.y) * wupB1;
  zB2 = (a2B.x + a2B.y) * wupB2;
}

// (512,4): 4 waves/EU = 16 waves/CU = exactly the 2 blocks/CU this grid achieves.
__global__ __launch_bounds__(BLOCK, 4) void qcnn_kernel(
    const float* __restrict__ x,   const float* __restrict__ fcw,
    const float* __restrict__ fcb, const float* __restrict__ qp,
    const float* __restrict__ pw,  const float* __restrict__ pb,
    float* __restrict__ out)
{
  __shared__ float s_fcw[8 * 512];        // [q][e]      16 KB
  __shared__ float s_pwt[8 * 512];        // [q][o] transposed  16 KB
  __shared__ float s_pb[512];             //              2 KB
  __shared__ float s_beta[256];           //              1 KB
  __shared__ float s_K3[8][4][16][4];     // [q][k2][u][j]  8 KB

  const int tid = threadIdx.x;
  const int wave = tid >> 6;
  const int lane = tid & 63;
  const int u = lane & 15;       // circuit bits 4..7
  const int g = lane >> 4;       // sample group within wave

  const int base = blockIdx.x * 64 + wave * 8;
  const int sA = base + g;
  const int sB = base + 4 + g;

  // ---- x prefetch FIRST: 16 global float4 in flight; HBM latency overlaps
  //      the entire prologue (staging + K build + 2 barriers) ----
  const float* xrA = x + (size_t)sA * 512 + u * 4;
  const float* xrB = x + (size_t)sB * 512 + u * 4;
  float4 xpa[8], xpb[8];
#pragma unroll
  for (int t = 0; t < 8; ++t) xpa[t] = *(const float4*)(xrA + t * 64);
#pragma unroll
  for (int t = 0; t < 8; ++t) xpb[t] = *(const float4*)(xrB + t * 64);

  // ---- prologue: all-coalesced global reads ----
  for (int i = tid; i < 1024; i += BLOCK)
    ((float4*)s_fcw)[i] = ((const float4*)fcw)[i];
  // pw natural [512][8] -> transposed s_pwt[q][o]; coalesced float4 read,
  // scalar ds_writes land 2-way per bank (free).
  for (int i = tid; i < 1024; i += BLOCK) {
    const float4 v = ((const float4*)pw)[i];   // row=i>>1, cols 4*(i&1)..+3
    const int row = i >> 1, c0 = 4 * (i & 1);
    s_pwt[(c0 + 0) * 512 + row] = v.x;
    s_pwt[(c0 + 1) * 512 + row] = v.y;
    s_pwt[(c0 + 2) * 512 + row] = v.z;
    s_pwt[(c0 + 3) * 512 + row] = v.w;
  }
  if (tid < 128) ((float4*)s_pb)[tid] = ((const float4*)pb)[tid];
  if (tid < 256) {
    const int c = tid;
    const int i1 = gmap(c);
    const int i2 = gmap(i1);
    float ang = 0.f;
#pragma unroll
    for (int q = 0; q < 8; ++q) {
      ang += (((c  >> q) & 1) ? 0.5f : -0.5f) * qp[q];
      ang += (((i1 >> q) & 1) ? 0.5f : -0.5f) * qp[8 + q];
      ang += (((i2 >> q) & 1) ? 0.5f : -0.5f) * qp[16 + q];
    }
    s_beta[c] = ang;
  }
  __syncthreads();

  // ---- K tables: K_q[c] = cos(beta[c^m_q] - beta[c]) / 256, float4-packed ----
  for (int i = tid; i < 2048; i += BLOCK) {
    const int q = i >> 8, c = i & 255;
    const int m = (int)((MQ_PACKED >> (8 * q)) & 0xFF);
    const float kv = __cosf(s_beta[c ^ m] - s_beta[c]) * (1.0f / 256.0f);
    s_K3[q][(c & 15) >> 2][c >> 4][c & 3] = kv;
  }
  __syncthreads();

  // ---- Phase A: angles via packed dot products from prefetched registers ----
  v2f accA[8], accB[8];
#pragma unroll
  for (int q = 0; q < 8; ++q) {
    accA[q].x = 0.f; accA[q].y = 0.f;
    accB[q].x = 0.f; accB[q].y = 0.f;
  }
#pragma unroll
  for (int t = 0; t < 8; ++t) {
    const float4 xa = xpa[t];
    const float4 xb = xpb[t];
    v2f xa01; xa01.x = xa.x; xa01.y = xa.y;
    v2f xa23; xa23.x = xa.z; xa23.y = xa.w;
    v2f xb01; xb01.x = xb.x; xb01.y = xb.y;
    v2f xb23; xb23.x = xb.z; xb23.y = xb.w;
#pragma unroll
    for (int q = 0; q < 8; ++q) {
      const float4 wv = *(const float4*)(s_fcw + q * 512 + u * 4 + t * 64);
      v2f w01; w01.x = wv.x; w01.y = wv.y;
      v2f w23; w23.x = wv.z; w23.y = wv.w;
      accA[q] = pk_fma(xa01, w01, accA[q]);
      accA[q] = pk_fma(xa23, w23, accA[q]);
      accB[q] = pk_fma(xb01, w01, accB[q]);
      accB[q] = pk_fma(xb23, w23, accB[q]);
    }
  }
  float thA[8], thB[8];
#pragma unroll
  for (int q = 0; q < 8; ++q) {
    float aA = accA[q].x + accA[q].y;
    float aB = accB[q].x + accB[q].y;
    aA += shx<1>(aA); aB += shx<1>(aB);
    aA += shx<2>(aA); aB += shx<2>(aB);
    aA += shx<4>(aA); aB += shx<4>(aB);
    aA += shx<8>(aA); aB += shx<8>(aB);
    const float fb = fcb[q];
    thA[q] = aA + fb; thB[q] = aB + fb;
  }

  // ---- Phase B: X-basis real product-state factors ----
  v2f wA[8], wB[8];
  float wupA[8], wupB[8];
  build_w(thA, u, wA, wupA);
  build_w(thB, u, wB, wupB);

  // ---- Phase C: z_q = sum_c w_c * w_{c^m_q} * K_q[c] ----
  float zpA[8], zpB[8];
  {
    const float4* kb4 = ((const float4*)s_K3) + u;
    dot1<0, 1, false>(kb4, wA, wB, wupA[0], wupB[0], zpA[0], zpB[0]);
    dot1<4, 1, true >(kb4, wA, wB, wupA[4], wupB[4], zpA[4], zpB[4]);
    dot2<1, 5, 3, false>(kb4, wA, wB, wupA[1], wupA[5], wupB[1], wupB[5],
                         zpA[1], zpA[5], zpB[1], zpB[5]);
    dot2<2, 6, 6, false>(kb4, wA, wB, wupA[2], wupA[6], wupB[2], wupB[6],
                         zpA[2], zpA[6], zpB[2], zpB[6]);
    dot2<3, 7, 4, true >(kb4, wA, wB, wupA[3], wupA[7], wupB[3], wupB[7],
                         zpA[3], zpA[7], zpB[3], zpB[7]);
  }
  // sum over the 16 lanes of the sample (result broadcast to all lanes)
#pragma unroll
  for (int q = 0; q < 8; ++q) { zpA[q] += shx<1>(zpA[q]); zpB[q] += shx<1>(zpB[q]); }
#pragma unroll
  for (int q = 0; q < 8; ++q) { zpA[q] += shx<2>(zpA[q]); zpB[q] += shx<2>(zpB[q]); }
#pragma unroll
  for (int q = 0; q < 8; ++q) { zpA[q] += shx<4>(zpA[q]); zpB[q] += shx<4>(zpB[q]); }
#pragma unroll
  for (int q = 0; q < 8; ++q) { zpA[q] += shx<8>(zpA[q]); zpB[q] += shx<8>(zpB[q]); }

  // ---- Phase E: out = z @ post_w^T + post_b, LDS reads shared by 2 rows.
  //      Non-temporal stores: out is write-once; keep it from evicting x
  //      (which is L3-resident across bench iterations) ----
  v2f zzA[8], zzB[8];
#pragma unroll
  for (int q = 0; q < 8; ++q) {
    zzA[q].x = zpA[q]; zzA[q].y = zpA[q];
    zzB[q].x = zpB[q]; zzB[q].y = zpB[q];
  }
  float* orA = out + (size_t)sA * 512;
  float* orB = out + (size_t)sB * 512;
#pragma unroll
  for (int tt = 0; tt < 8; ++tt) {
    const int o = u * 4 + tt * 64;
    const float4 pbv = *(const float4*)(s_pb + o);
    v2f rA0; rA0.x = pbv.x; rA0.y = pbv.y;
    v2f rA1; rA1.x = pbv.z; rA1.y = pbv.w;
    v2f rB0 = rA0, rB1 = rA1;
#pragma unroll
    for (int q = 0; q < 8; ++q) {
      const float4 wv = *(const float4*)(s_pwt + q * 512 + o);
      v2f w01; w01.x = wv.x; w01.y = wv.y;
      v2f w23; w23.x = wv.z; w23.y = wv.w;
      rA0 = pk_fma(zzA[q], w01, rA0);
      rA1 = pk_fma(zzA[q], w23, rA1);
      rB0 = pk_fma(zzB[q], w01, rB0);
      rB1 = pk_fma(zzB[q], w23, rB1);
    }
    v4f ovA; ovA.x = rA0.x; ovA.y = rA0.y; ovA.z = rA1.x; ovA.w = rA1.y;
    v4f ovB; ovB.x = rB0.x; ovB.y = rB0.y; ovB.z = rB1.x; ovB.w = rB1.y;
    __builtin_nontemporal_store(ovA, (v4f*)(orA + o));
    __builtin_nontemporal_store(ovB, (v4f*)(orB + o));
  }
}

extern "C" void kernel_launch(void* const* d_in, const int* in_sizes, int n_in,
                              void* d_out, int out_size, void* d_ws, size_t ws_size,
                              hipStream_t stream) {
  const float* x   = (const float*)d_in[0];
  const float* fcw = (const float*)d_in[1];
  const float* fcb = (const float*)d_in[2];
  const float* qp  = (const float*)d_in[3];
  const float* pw  = (const float*)d_in[4];
  const float* pb  = (const float*)d_in[5];
  float* out = (float*)d_out;

  // 32768 samples / (8 per wave * 8 waves per block) = 512 blocks
  dim3 grid(512), block(BLOCK);
  hipLaunchKernelGGL(qcnn_kernel, grid, block, 0, stream, x, fcw, fcb, qp, pw, pb, out);
}